// Round 1
// baseline (212.445 us; speedup 1.0000x reference)
//
#include <hip/hip_runtime.h>
#include <hip/hip_bf16.h>

#define WS 16
#define C1 6.5025f      // (0.01*255)^2
#define C2 58.5225f     // (0.03*255)^2

// Stage 1: one workgroup per (batch, block-row). 256 threads.
// Thread tid: h_local = tid>>7 (0/1), w4 = tid&127 -> w = 4*w4 (fixed per thread).
// Accumulates 5 sums over c in [0,3), 8 row-pairs. Fully coalesced float4 loads.
__global__ __launch_bounds__(256) void ssim_stage1(
    const float* __restrict__ x, const float* __restrict__ y,
    float* __restrict__ partial)
{
    const int wg  = blockIdx.x;          // 0..1023
    const int b   = wg >> 5;             // batch 0..31
    const int bh  = wg & 31;             // block-row 0..31
    const int tid = threadIdx.x;
    const int h_local = tid >> 7;        // 0 or 1
    const int w4 = tid & 127;            // float4 column index
    const int w  = w4 << 2;              // 0..508
    const int bw = w >> 4;               // 0..31 (fixed per thread)

    float sx = 0.f, sy = 0.f, sxx = 0.f, syy = 0.f, sxy = 0.f;

    const size_t batch_off = (size_t)b * 3u * 512u * 512u;
    const int h0 = bh * WS + h_local;

    #pragma unroll
    for (int c = 0; c < 3; ++c) {
        #pragma unroll
        for (int hp = 0; hp < 8; ++hp) {
            const int h = h0 + hp * 2;
            const size_t off = batch_off + ((size_t)c * 512u + (size_t)h) * 512u + (size_t)w;
            const float4 xv = *reinterpret_cast<const float4*>(x + off);
            const float4 yv = *reinterpret_cast<const float4*>(y + off);
            sx += (xv.x + xv.y) + (xv.z + xv.w);
            sy += (yv.x + yv.y) + (yv.z + yv.w);
            sxx = fmaf(xv.x, xv.x, sxx); sxx = fmaf(xv.y, xv.y, sxx);
            sxx = fmaf(xv.z, xv.z, sxx); sxx = fmaf(xv.w, xv.w, sxx);
            syy = fmaf(yv.x, yv.x, syy); syy = fmaf(yv.y, yv.y, syy);
            syy = fmaf(yv.z, yv.z, syy); syy = fmaf(yv.w, yv.w, syy);
            sxy = fmaf(xv.x, yv.x, sxy); sxy = fmaf(xv.y, yv.y, sxy);
            sxy = fmaf(xv.z, yv.z, sxy); sxy = fmaf(xv.w, yv.w, sxy);
        }
    }

    // Reduce across the 4 lanes sharing a bw (lane xor 1, 2 stay within the quad).
    #pragma unroll
    for (int d = 1; d < 4; d <<= 1) {
        sx  += __shfl_xor(sx,  d);
        sy  += __shfl_xor(sy,  d);
        sxx += __shfl_xor(sxx, d);
        syy += __shfl_xor(syy, d);
        sxy += __shfl_xor(sxy, d);
    }

    // Two h_local slices write disjoint LDS slots -> no atomics, deterministic.
    __shared__ float sums[2][32][5];
    if ((tid & 3) == 0) {
        sums[h_local][bw][0] = sx;
        sums[h_local][bw][1] = sy;
        sums[h_local][bw][2] = sxx;
        sums[h_local][bw][3] = syy;
        sums[h_local][bw][4] = sxy;
    }
    __syncthreads();

    if (tid < 32) {
        const float Sx  = sums[0][tid][0] + sums[1][tid][0];
        const float Sy  = sums[0][tid][1] + sums[1][tid][1];
        const float Sxx = sums[0][tid][2] + sums[1][tid][2];
        const float Syy = sums[0][tid][3] + sums[1][tid][3];
        const float Sxy = sums[0][tid][4] + sums[1][tid][4];

        const float inv = 1.0f / 256.0f;     // ws*ws (NOT ws*ws*channels; faithful to ref)
        const float mx  = Sx * inv;
        const float my  = Sy * inv;
        const float mx2 = mx * mx;
        const float my2 = my * my;
        const float vx  = Sxx * inv - mx2;
        const float vy  = Syy * inv - my2;
        const float cxy = Sxy * inv - mx * my;

        const float num  = (2.0f * mx * my + C1) * (2.0f * cxy + C2);
        const float den  = (mx2 + my2 + C1) * (vx + vy + C2);
        float ssim = num / den;

        // Reduce 32 values (lanes 0..31 of wave 0).
        #pragma unroll
        for (int d = 1; d < 32; d <<= 1) ssim += __shfl_xor(ssim, d);
        if (tid == 0) partial[wg] = ssim;
    }
}

// Stage 2: one block per batch, reduce 32 partials -> (1 - mean)/2.
__global__ __launch_bounds__(64) void ssim_stage2(
    const float* __restrict__ partial, float* __restrict__ out)
{
    const int b = blockIdx.x;
    const int lane = threadIdx.x;
    float v = (lane < 32) ? partial[b * 32 + lane] : 0.f;
    #pragma unroll
    for (int d = 1; d < 64; d <<= 1) v += __shfl_xor(v, d);
    if (lane == 0) {
        const float mean_ssim = v * (1.0f / 1024.0f);  // 32*32 blocks per batch
        out[b] = (1.0f - mean_ssim) * 0.5f;
    }
}

extern "C" void kernel_launch(void* const* d_in, const int* in_sizes, int n_in,
                              void* d_out, int out_size, void* d_ws, size_t ws_size,
                              hipStream_t stream) {
    const float* x = (const float*)d_in[0];
    const float* y = (const float*)d_in[1];
    float* out = (float*)d_out;
    float* partial = (float*)d_ws;   // 1024 floats

    ssim_stage1<<<1024, 256, 0, stream>>>(x, y, partial);
    ssim_stage2<<<32, 64, 0, stream>>>(partial, out);
}